// Round 1
// baseline (536.401 us; speedup 1.0000x reference)
//
#include <hip/hip_runtime.h>
#include <stdint.h>

#define CA 64     // in channels
#define CB 128    // out channels
#define KOFF 27   // 3^3 offsets
#define BN_EPS 1e-4f

typedef short bf16x8 __attribute__((ext_vector_type(8)));
typedef float f32x4 __attribute__((ext_vector_type(4)));
typedef unsigned int u32x4 __attribute__((ext_vector_type(4)));
typedef unsigned short u16x4 __attribute__((ext_vector_type(4)));

__device__ __forceinline__ unsigned short f2bf(float f) {
  union { float f; uint32_t u; } c; c.f = f;
  uint32_t u = c.u;
  return (unsigned short)((u + 0x7FFFu + ((u >> 16) & 1u)) >> 16);  // RNE
}

// Barrier WITHOUT vmcnt drain: LDS visibility only. Safe because all cross-wave
// data flows through LDS (ds_write -> lgkmcnt(0) -> s_barrier); in-flight global
// loads target VGPRs only and must stay in flight (that's the pipeline).
__device__ __forceinline__ void barrier_lds() {
  asm volatile("s_waitcnt lgkmcnt(0)\n\ts_barrier" ::: "memory");
}

// ---- mask dtype detection: if int32 layout, bytes at i%4!=0 are all zero ----
__global__ void detect_mask_k(const unsigned char* __restrict__ m, int* flag) {
  unsigned v = 0;
  for (int i = threadIdx.x; i < 4096; i += 256)
    if (i & 3) v |= m[i];
  if (v) atomicOr(flag, 1);   // 1 => byte/bool layout, 0 => int32 layout
}

__global__ void pack_mask_k(const void* __restrict__ mp, const int* __restrict__ flag,
                            uint32_t* __restrict__ bits, int n) {
  int i = blockIdx.x * blockDim.x + threadIdx.x;
  if (i >= n) return;
  uint32_t b = 0;
  if (*flag) {
    const unsigned char* m = (const unsigned char*)mp + (size_t)i * KOFF;
    for (int k = 0; k < KOFF; k++) b |= (m[k] ? 1u : 0u) << k;
  } else {
    const int* m = (const int*)mp + (size_t)i * KOFF;
    for (int k = 0; k < KOFF; k++) b |= (m[k] ? 1u : 0u) << k;
  }
  bits[i] = b;
}

// ---- all weight transposes + bf16 convert in one launch ----
// wt[k][co][ci] = bf16(w[k][ci][co])
__global__ void transpose_all_k(const float* __restrict__ W1, const float* __restrict__ W2,
                                const float* __restrict__ Wnin,
                                unsigned short* __restrict__ w1t, unsigned short* __restrict__ w2t,
                                unsigned short* __restrict__ wnt) {
  const int t1 = KOFF * CA * CB, t2 = KOFF * CB * CB, t3 = CA * CB;
  int idx = blockIdx.x * blockDim.x + threadIdx.x;
  if (idx < t1) {
    int ci = idx % CA; int r = idx / CA; int co = r % CB; int k = r / CB;
    w1t[idx] = f2bf(W1[((size_t)k * CA + ci) * CB + co]);
  } else if (idx < t1 + t2) {
    int j = idx - t1;
    int ci = j % CB; int r = j / CB; int co = r % CB; int k = r / CB;
    w2t[j] = f2bf(W2[((size_t)k * CB + ci) * CB + co]);
  } else if (idx < t1 + t2 + t3) {
    int j = idx - t1 - t2;
    int ci = j % CA; int co = j / CA;
    wnt[j] = f2bf(Wnin[(size_t)ci * CB + co]);
  }
}

// ---- per-channel sum & sumsq (training-mode BN stats) ----
template<int C>
__global__ void col_stats_k(const float* __restrict__ x, int n, float* __restrict__ sums) {
  __shared__ float ssum[C], ssq[C];
  int t = threadIdx.x;
  for (int i = t; i < C; i += 256) { ssum[i] = 0.f; ssq[i] = 0.f; }
  __syncthreads();
  const int c = t % C;
  const int rpb = 256 / C;
  float s = 0.f, q = 0.f;
  for (int r = blockIdx.x * rpb + t / C; r < n; r += gridDim.x * rpb) {
    float v = x[(size_t)r * C + c];
    s += v; q += v * v;
  }
  atomicAdd(&ssum[c], s);
  atomicAdd(&ssq[c], q);
  __syncthreads();
  for (int i = t; i < C; i += 256) {
    atomicAdd(&sums[i], ssum[i]);
    atomicAdd(&sums[C + i], ssq[i]);
  }
}

template<int C>
__global__ void bn_finalize_k(const float* __restrict__ sums, const float* __restrict__ gamma,
                              const float* __restrict__ beta, float* __restrict__ sc, int n) {
  int c = threadIdx.x;
  if (c >= C) return;
  float inv_n = 1.f / (float)n;
  float mean = sums[c] * inv_n;
  float var = sums[C + c] * inv_n - mean * mean;
  float rstd = rsqrtf(var + BN_EPS);
  float scale = gamma[c] * rstd;
  sc[c] = scale;
  sc[C + c] = beta[c] - mean * scale;
}

template<int C, bool RAW>
__global__ void bn_apply_k(const float* __restrict__ x, const float* __restrict__ sc,
                           unsigned short* __restrict__ h, unsigned short* __restrict__ raw,
                           int total) {
  int idx = (blockIdx.x * blockDim.x + threadIdx.x) * 4;
  if (idx >= total) return;
  f32x4 v = *(const f32x4*)&x[idx];
  int c0 = idx % C;
  u16x4 ho, ro;
#pragma unroll
  for (int j = 0; j < 4; j++) {
    float s = sc[c0 + j], b = sc[C + c0 + j];
    float hv = fmaxf(v[j] * s + b, 0.f);
    ho[j] = f2bf(hv);
    if (RAW) ro[j] = f2bf(v[j]);
  }
  *(u16x4*)&h[idx] = ho;
  if (RAW) *(u16x4*)&raw[idx] = ro;
}

// ---- pipelined gather-GEMM subconv ----
// out[n,:] = sum_k mask[n,k] * hin[nbr[n,k],:] @ W[k]   (+ FUSE: fbraw @ wnt)
// Block: 64 rows x 128 cols, 256 threads (4 waves of 64x32).
// 2-deep gather pipeline: the ds_write of tile(k+1) consumes loads issued at
// iteration k-2 (~2 iterations = ~1000cy of latency cover). B-fragments are
// single-deep (weights are L2-resident). LDS tile is unpadded + XOR-swizzled
// in 16B chunks (chunk ^ (row & (CH-1))) on BOTH write and read sides ->
// bank-balanced and 39.9KB/block for CIN=128 -> 4 blocks/CU.
// STATS: fuse per-channel sum/sumsq (for the next BN) into the epilogue.
template<int CIN, bool FUSE, bool STATS>
__launch_bounds__(256, 4)
__global__ void conv_k(const unsigned short* __restrict__ hin,
                       const unsigned short* __restrict__ wt,
                       const int* __restrict__ nbr,
                       const uint32_t* __restrict__ mbits,
                       const unsigned short* __restrict__ fbraw,
                       const unsigned short* __restrict__ wnt,
                       float* __restrict__ out, float* __restrict__ sums, int n) {
  constexpr int TR = 64;
  constexpr int NKS = CIN / 32;     // MFMA K-steps per offset (2 or 4)
  constexpr int CH = CIN / 8;       // 16B chunks per row (8 or 16)
  constexpr int RPP = 256 / CH;     // rows per staging pass
  constexpr int NP = TR / RPP;      // staging passes per thread (2 or 4)

  __shared__ alignas(16) unsigned short tile[2][TR * CIN];
  __shared__ int lnbr[TR * KOFF];   // pre-multiplied byte offsets
  __shared__ uint32_t lmb[TR];

  const int t = threadIdx.x;
  const int rowbase = blockIdx.x * TR;
  const int nrows = min(TR, n - rowbase);

  for (int i = t; i < nrows * KOFF; i += 256)
    lnbr[i] = nbr[(size_t)rowbase * KOFF + i] * (CIN * 2);
  if (t < TR) lmb[t] = (t < nrows) ? mbits[rowbase + t] : 0u;
  barrier_lds();

  const int lane = t & 63;
  const int wave = t >> 6;
  const int l16 = lane & 15;
  const int quad = lane >> 4;
  const int colbase = wave * 32;
  const int c16 = t % CH;           // 16B chunk index within row
  const int grow = t / CH;
  const int boff0 = (colbase + l16) * CIN + quad * 8;
  const int boff1 = boff0 + 16 * CIN;

  int toff[NP]; int pnb[NP]; uint32_t pmb[NP];
#pragma unroll
  for (int p = 0; p < NP; p++) {
    int r = p * RPP + grow;
    toff[p] = r * CIN + ((c16 ^ (r & (CH - 1))) * 8);  // swizzled write offset
    pnb[p] = r * KOFF;
    pmb[p] = lmb[r];
  }

  f32x4 acc[4][2];
#pragma unroll
  for (int i = 0; i < 4; i++) { acc[i][0] = f32x4{0,0,0,0}; acc[i][1] = f32x4{0,0,0,0}; }

  bf16x8 bfr[2 * NKS];   // single-deep B fragments
  u32x4 gr[2][NP];       // 2-deep gather pipeline
  u32x4 g0[NP];          // prologue-only

#define LOADB(kk, dst)                                                         \
  {                                                                            \
    const unsigned short* wk = wt + (size_t)(kk) * (CB * CIN);                 \
    _Pragma("unroll")                                                          \
    for (int ks = 0; ks < NKS; ks++) {                                         \
      dst[2 * ks]     = *(const bf16x8*)&wk[boff0 + ks * 32];                  \
      dst[2 * ks + 1] = *(const bf16x8*)&wk[boff1 + ks * 32];                  \
    }                                                                          \
  }

#define GATHER(kk, dst)                                                        \
  {                                                                            \
    _Pragma("unroll")                                                          \
    for (int p = 0; p < NP; p++) {                                             \
      u32x4 v = {0, 0, 0, 0};                                                  \
      if ((pmb[p] >> (kk)) & 1u)                                               \
        v = *(const u32x4*)((const char*)hin +                                 \
                            (size_t)(unsigned)lnbr[pnb[p] + (kk)] + c16 * 16); \
      dst[p] = v;                                                              \
    }                                                                          \
  }

#define STAGE(buf, src)                                                        \
  {                                                                            \
    _Pragma("unroll")                                                          \
    for (int p = 0; p < NP; p++) *(u32x4*)&tile[buf][toff[p]] = src[p];        \
  }

#define MMA(buf)                                                               \
  {                                                                            \
    _Pragma("unroll")                                                          \
    for (int ks = 0; ks < NKS; ks++) {                                         \
      _Pragma("unroll")                                                        \
      for (int rt = 0; rt < 4; rt++) {                                         \
        int row = rt * 16 + l16;                                               \
        bf16x8 a = *(const bf16x8*)&tile[buf][row * CIN +                      \
                      (((ks * 4 + quad) ^ (row & (CH - 1))) * 8)];             \
        acc[rt][0] = __builtin_amdgcn_mfma_f32_16x16x32_bf16(a, bfr[2 * ks],     acc[rt][0], 0, 0, 0); \
        acc[rt][1] = __builtin_amdgcn_mfma_f32_16x16x32_bf16(a, bfr[2 * ks + 1], acc[rt][1], 0, 0, 0); \
      }                                                                        \
    }                                                                          \
  }

  // ---- prologue ----
  LOADB(0, bfr);
  GATHER(0, g0);

  if constexpr (FUSE) {
    // NiN shortcut: acc += fbraw @ wnt, A-frags straight from global (the 16B
    // A-fragment IS a contiguous row chunk) -- no ftile staging, covers g(0).
#pragma unroll
    for (int ks = 0; ks < CA / 32; ks++) {
      bf16x8 b0 = *(const bf16x8*)&wnt[(colbase + l16) * CA + ks * 32 + quad * 8];
      bf16x8 b1 = *(const bf16x8*)&wnt[(colbase + 16 + l16) * CA + ks * 32 + quad * 8];
#pragma unroll
      for (int rt = 0; rt < 4; rt++) {
        int r = rt * 16 + l16;
        bf16x8 a = bf16x8{0, 0, 0, 0, 0, 0, 0, 0};
        if (r < nrows)
          a = *(const bf16x8*)&fbraw[(size_t)(rowbase + r) * CA + ks * 32 + quad * 8];
        acc[rt][0] = __builtin_amdgcn_mfma_f32_16x16x32_bf16(a, b0, acc[rt][0], 0, 0, 0);
        acc[rt][1] = __builtin_amdgcn_mfma_f32_16x16x32_bf16(a, b1, acc[rt][1], 0, 0, 0);
      }
    }
  }

  STAGE(0, g0);            // waits on g(0) only (covered by NiN when FUSE)
  GATHER(1, gr[0]);        // issued after the stage -> stays in flight
  GATHER(2, gr[1]);        // across the barrier
  barrier_lds();

  // ---- main loop, fully unrolled so buffer indices fold to registers ----
#pragma unroll
  for (int k = 0; k < KOFF; k++) {
    const int cur = k & 1, nxt = cur ^ 1;
    MMA(cur);
    if (k + 1 < KOFF) {
      LOADB(k + 1, bfr);               // L2-hot, covered to next iteration
      STAGE(nxt, gr[cur]);             // g(k+1): loaded 2 iterations ago
      if (k + 3 < KOFF) GATHER(k + 3, gr[cur]);
      barrier_lds();
    }
  }
#undef LOADB
#undef GATHER
#undef STAGE
#undef MMA

  // epilogue: C/D layout col=lane&15, row=(lane>>4)*4+reg
#pragma unroll
  for (int rt = 0; rt < 4; rt++) {
#pragma unroll
    for (int ct = 0; ct < 2; ct++) {
#pragma unroll
      for (int i = 0; i < 4; i++) {
        int r = rt * 16 + quad * 4 + i;
        if (r < nrows) {
          int c = colbase + ct * 16 + l16;
          out[(size_t)(rowbase + r) * CB + c] = acc[rt][ct][i];
        }
      }
    }
  }

  if constexpr (STATS) {
    // fused next-BN stats: tail rows contribute exact zeros (masked gathers)
#pragma unroll
    for (int ct = 0; ct < 2; ct++) {
      float s = 0.f, q = 0.f;
#pragma unroll
      for (int rt = 0; rt < 4; rt++)
#pragma unroll
        for (int i = 0; i < 4; i++) { float v = acc[rt][ct][i]; s += v; q += v * v; }
      s += __shfl_xor(s, 16); s += __shfl_xor(s, 32);   // reduce over quad lanes
      q += __shfl_xor(q, 16); q += __shfl_xor(q, 32);
      if (quad == 0) {
        int cch = colbase + ct * 16 + l16;
        atomicAdd(&sums[cch], s);
        atomicAdd(&sums[CB + cch], q);
      }
    }
  }
}

extern "C" void kernel_launch(void* const* d_in, const int* in_sizes, int n_in,
                              void* d_out, int out_size, void* d_ws, size_t ws_size,
                              hipStream_t stream) {
  const float* feat   = (const float*)d_in[0];
  const float* gamma1 = (const float*)d_in[1];
  const float* beta1  = (const float*)d_in[2];
  const float* W1     = (const float*)d_in[3];
  const float* gamma2 = (const float*)d_in[4];
  const float* beta2  = (const float*)d_in[5];
  const float* W2     = (const float*)d_in[6];
  const float* Wnin   = (const float*)d_in[7];
  const int*   nbr    = (const int*)d_in[8];
  const void*  mask   = d_in[9];
  float* out = (float*)d_out;

  const int n = in_sizes[0] / CA;  // 100000

  char* ws = (char*)d_ws;
  size_t off = 0;
  auto alloc = [&](size_t bytes) { size_t p = off; off += (bytes + 255) & ~(size_t)255; return p; };
  int*            flag  = (int*)           (ws + alloc(256));
  float*          sums1 = (float*)         (ws + alloc(2 * CA * 4));
  float*          sums2 = (float*)         (ws + alloc(2 * CB * 4));
  float*          sc1   = (float*)         (ws + alloc(2 * CA * 4));
  float*          sc2   = (float*)         (ws + alloc(2 * CB * 4));
  uint32_t*       mbits = (uint32_t*)      (ws + alloc((size_t)n * 4));
  unsigned short* fb    = (unsigned short*)(ws + alloc((size_t)n * CA * 2));
  unsigned short* hb1   = (unsigned short*)(ws + alloc((size_t)n * CA * 2));
  float*          out1  = (float*)         (ws + alloc((size_t)n * CB * 4));
  unsigned short* hb2   = (unsigned short*)(ws + alloc((size_t)n * CB * 2));
  unsigned short* w1t   = (unsigned short*)(ws + alloc((size_t)KOFF * CB * CA * 2));
  unsigned short* w2t   = (unsigned short*)(ws + alloc((size_t)KOFF * CB * CB * 2));
  unsigned short* wnt   = (unsigned short*)(ws + alloc((size_t)CB * CA * 2));

  // zero flag + stats accumulators (ws is poisoned 0xAA before every launch)
  hipMemsetAsync(d_ws, 0, 1792, stream);

  detect_mask_k<<<1, 256, 0, stream>>>((const unsigned char*)mask, flag);
  pack_mask_k<<<(n + 255) / 256, 256, 0, stream>>>(mask, flag, mbits, n);

  {
    int tot = KOFF * CA * CB + KOFF * CB * CB + CA * CB;
    transpose_all_k<<<(tot + 255) / 256, 256, 0, stream>>>(W1, W2, Wnin, w1t, w2t, wnt);
  }

  // stage 1: BN stats -> scale/shift -> h1 (bn+relu bf16) + raw feat bf16
  col_stats_k<CA><<<256, 256, 0, stream>>>(feat, n, sums1);
  bn_finalize_k<CA><<<1, CA, 0, stream>>>(sums1, gamma1, beta1, sc1, n);
  bn_apply_k<CA, true><<<(n * CA / 4 + 255) / 256, 256, 0, stream>>>(feat, sc1, hb1, fb, n * CA);

  // conv1: out1 = subconv(h1, W1)  [N,128] fp32, BN2 stats fused in epilogue
  conv_k<CA, false, true><<<(n + 63) / 64, 256, 0, stream>>>(hb1, w1t, nbr, mbits, nullptr, nullptr, out1, sums2, n);

  // stage 2 (col_stats pass eliminated -- stats came from conv1)
  bn_finalize_k<CB><<<1, CB, 0, stream>>>(sums2, gamma2, beta2, sc2, n);
  bn_apply_k<CB, false><<<(n * CB / 4 + 255) / 256, 256, 0, stream>>>(out1, sc2, hb2, nullptr, n * CB);

  // conv2 + fused NiN shortcut
  conv_k<CB, true, false><<<(n + 63) / 64, 256, 0, stream>>>(hb2, w2t, nbr, mbits, fb, wnt, out, nullptr, n);
}

// Round 2
// 509.258 us; speedup vs baseline: 1.0533x; 1.0533x over previous
//
#include <hip/hip_runtime.h>
#include <stdint.h>

#define CA 64     // in channels
#define CB 128    // out channels
#define KOFF 27   // 3^3 offsets
#define BN_EPS 1e-4f

typedef short bf16x8 __attribute__((ext_vector_type(8)));
typedef float f32x4 __attribute__((ext_vector_type(4)));
typedef unsigned int u32x4 __attribute__((ext_vector_type(4)));
typedef unsigned short u16x4 __attribute__((ext_vector_type(4)));

__device__ __forceinline__ unsigned short f2bf(float f) {
  union { float f; uint32_t u; } c; c.f = f;
  uint32_t u = c.u;
  return (unsigned short)((u + 0x7FFFu + ((u >> 16) & 1u)) >> 16);  // RNE
}

// Barrier WITHOUT vmcnt drain: LDS visibility only. Safe because all cross-wave
// data flows through LDS (ds_write -> lgkmcnt(0) -> s_barrier); in-flight global
// loads target VGPRs only and must stay in flight (that's the pipeline).
__device__ __forceinline__ void barrier_lds() {
  asm volatile("s_waitcnt lgkmcnt(0)\n\ts_barrier" ::: "memory");
}

// ---- mask dtype detection: if int32 layout, bytes at i%4!=0 are all zero ----
__global__ void detect_mask_k(const unsigned char* __restrict__ m, int* flag) {
  unsigned v = 0;
  for (int i = threadIdx.x; i < 4096; i += 256)
    if (i & 3) v |= m[i];
  if (v) atomicOr(flag, 1);   // 1 => byte/bool layout, 0 => int32 layout
}

__global__ void pack_mask_k(const void* __restrict__ mp, const int* __restrict__ flag,
                            uint32_t* __restrict__ bits, int n) {
  int i = blockIdx.x * blockDim.x + threadIdx.x;
  if (i >= n) return;
  uint32_t b = 0;
  if (*flag) {
    const unsigned char* m = (const unsigned char*)mp + (size_t)i * KOFF;
    for (int k = 0; k < KOFF; k++) b |= (m[k] ? 1u : 0u) << k;
  } else {
    const int* m = (const int*)mp + (size_t)i * KOFF;
    for (int k = 0; k < KOFF; k++) b |= (m[k] ? 1u : 0u) << k;
  }
  bits[i] = b;
}

// ---- all weight transposes + bf16 convert in one launch ----
// wt[k][co][ci] = bf16(w[k][ci][co])
__global__ void transpose_all_k(const float* __restrict__ W1, const float* __restrict__ W2,
                                const float* __restrict__ Wnin,
                                unsigned short* __restrict__ w1t, unsigned short* __restrict__ w2t,
                                unsigned short* __restrict__ wnt) {
  const int t1 = KOFF * CA * CB, t2 = KOFF * CB * CB, t3 = CA * CB;
  int idx = blockIdx.x * blockDim.x + threadIdx.x;
  if (idx < t1) {
    int ci = idx % CA; int r = idx / CA; int co = r % CB; int k = r / CB;
    w1t[idx] = f2bf(W1[((size_t)k * CA + ci) * CB + co]);
  } else if (idx < t1 + t2) {
    int j = idx - t1;
    int ci = j % CB; int r = j / CB; int co = r % CB; int k = r / CB;
    w2t[j] = f2bf(W2[((size_t)k * CB + ci) * CB + co]);
  } else if (idx < t1 + t2 + t3) {
    int j = idx - t1 - t2;
    int ci = j % CA; int co = j / CA;
    wnt[j] = f2bf(Wnin[(size_t)ci * CB + co]);
  }
}

// ---- per-channel sum & sumsq (training-mode BN stats) ----
template<int C>
__global__ void col_stats_k(const float* __restrict__ x, int n, float* __restrict__ sums) {
  __shared__ float ssum[C], ssq[C];
  int t = threadIdx.x;
  for (int i = t; i < C; i += 256) { ssum[i] = 0.f; ssq[i] = 0.f; }
  __syncthreads();
  const int c = t % C;
  const int rpb = 256 / C;
  float s = 0.f, q = 0.f;
  for (int r = blockIdx.x * rpb + t / C; r < n; r += gridDim.x * rpb) {
    float v = x[(size_t)r * C + c];
    s += v; q += v * v;
  }
  atomicAdd(&ssum[c], s);
  atomicAdd(&ssq[c], q);
  __syncthreads();
  for (int i = t; i < C; i += 256) {
    atomicAdd(&sums[i], ssum[i]);
    atomicAdd(&sums[C + i], ssq[i]);
  }
}

template<int C>
__global__ void bn_finalize_k(const float* __restrict__ sums, const float* __restrict__ gamma,
                              const float* __restrict__ beta, float* __restrict__ sc, int n) {
  int c = threadIdx.x;
  if (c >= C) return;
  float inv_n = 1.f / (float)n;
  float mean = sums[c] * inv_n;
  float var = sums[C + c] * inv_n - mean * mean;
  float rstd = rsqrtf(var + BN_EPS);
  float scale = gamma[c] * rstd;
  sc[c] = scale;
  sc[C + c] = beta[c] - mean * scale;
}

template<int C, bool RAW>
__global__ void bn_apply_k(const float* __restrict__ x, const float* __restrict__ sc,
                           unsigned short* __restrict__ h, unsigned short* __restrict__ raw,
                           int total) {
  int idx = (blockIdx.x * blockDim.x + threadIdx.x) * 4;
  if (idx >= total) return;
  f32x4 v = *(const f32x4*)&x[idx];
  int c0 = idx % C;
  u16x4 ho, ro;
#pragma unroll
  for (int j = 0; j < 4; j++) {
    float s = sc[c0 + j], b = sc[C + c0 + j];
    float hv = fmaxf(v[j] * s + b, 0.f);
    ho[j] = f2bf(hv);
    if (RAW) ro[j] = f2bf(v[j]);
  }
  *(u16x4*)&h[idx] = ho;
  if (RAW) *(u16x4*)&raw[idx] = ro;
}

// ---- pipelined gather-GEMM subconv ----
// out[n,:] = sum_k mask[n,k] * hin[nbr[n,k],:] @ W[k]   (+ FUSE: fbraw @ wnt)
// Block: 64 rows x 128 cols, 256 threads (4 waves of 64x32).
// 2-deep gather pipeline (named grA/grB, manual unroll-by-2 so ALL register
// array indices are compile-time -- no dynamic indexing, no scratch). B-frags
// single-deep, reloaded each k (weights L2-hot). LDS tile unpadded, XOR
// chunk-swizzled (chunk ^ (row & (CH-1)), same involution on write & read) ->
// 0 bank conflicts measured, 39.9KB/block for CIN=128.
// No forced min-occupancy: R1 showed __launch_bounds__(256,4) causes a 16-dword
// scratch spill (WRITE_SIZE +64B/thread) that costs far more than occupancy.
template<int CIN, bool FUSE, bool STATS>
__launch_bounds__(256)
__global__ void conv_k(const unsigned short* __restrict__ hin,
                       const unsigned short* __restrict__ wt,
                       const int* __restrict__ nbr,
                       const uint32_t* __restrict__ mbits,
                       const unsigned short* __restrict__ fbraw,
                       const unsigned short* __restrict__ wnt,
                       float* __restrict__ out, float* __restrict__ sums, int n) {
  constexpr int TR = 64;
  constexpr int NKS = CIN / 32;     // MFMA K-steps per offset (2 or 4)
  constexpr int CH = CIN / 8;       // 16B chunks per row (8 or 16)
  constexpr int RPP = 256 / CH;     // rows per staging pass
  constexpr int NP = TR / RPP;      // staging passes per thread (2 or 4)

  __shared__ alignas(16) unsigned short tile[2][TR * CIN];
  __shared__ int lnbr[TR * KOFF];   // pre-multiplied byte offsets
  __shared__ uint32_t lmb[TR];

  const int t = threadIdx.x;
  const int rowbase = blockIdx.x * TR;
  const int nrows = min(TR, n - rowbase);

  for (int i = t; i < nrows * KOFF; i += 256)
    lnbr[i] = nbr[(size_t)rowbase * KOFF + i] * (CIN * 2);
  if (t < TR) lmb[t] = (t < nrows) ? mbits[rowbase + t] : 0u;
  barrier_lds();

  const int lane = t & 63;
  const int wave = t >> 6;
  const int l16 = lane & 15;
  const int quad = lane >> 4;
  const int colbase = wave * 32;
  const int c16 = t % CH;           // 16B chunk index within row
  const int grow = t / CH;          // row within a staging pass
  const int boff0 = (colbase + l16) * CIN + quad * 8;
  const int boff1 = boff0 + 16 * CIN;
  // RPP is a multiple of CH, so (p*RPP+grow)&(CH-1) == grow&(CH-1):
  // swizzle term is p-invariant -> single base + compile-time p offsets.
  const int tbase = grow * CIN + ((c16 ^ (grow & (CH - 1))) * 8);
  const int growK = grow * KOFF;

  uint32_t pmb[NP];
#pragma unroll
  for (int p = 0; p < NP; p++) pmb[p] = lmb[p * RPP + grow];

  f32x4 acc[4][2];
#pragma unroll
  for (int i = 0; i < 4; i++) { acc[i][0] = f32x4{0,0,0,0}; acc[i][1] = f32x4{0,0,0,0}; }

  bf16x8 bfr[2 * NKS];     // single-deep B fragments
  u32x4 grA[NP], grB[NP];  // named 2-deep gather pipeline (static indexing)

#define LOADB(kk, dst)                                                         \
  {                                                                            \
    const unsigned short* wk = wt + (size_t)(kk) * (CB * CIN);                 \
    _Pragma("unroll")                                                          \
    for (int ks = 0; ks < NKS; ks++) {                                         \
      dst[2 * ks]     = *(const bf16x8*)&wk[boff0 + ks * 32];                  \
      dst[2 * ks + 1] = *(const bf16x8*)&wk[boff1 + ks * 32];                  \
    }                                                                          \
  }

#define GATHER(kk, dst)                                                        \
  {                                                                            \
    _Pragma("unroll")                                                          \
    for (int p = 0; p < NP; p++) {                                             \
      u32x4 v = {0, 0, 0, 0};                                                  \
      if ((pmb[p] >> (kk)) & 1u)                                               \
        v = *(const u32x4*)((const char*)hin +                                 \
             (size_t)(unsigned)lnbr[p * RPP * KOFF + growK + (kk)] + c16 * 16);\
      dst[p] = v;                                                              \
    }                                                                          \
  }

#define STAGE(buf, src)                                                        \
  {                                                                            \
    _Pragma("unroll")                                                          \
    for (int p = 0; p < NP; p++)                                               \
      *(u32x4*)&tile[buf][tbase + p * RPP * CIN] = src[p];                     \
  }

#define MMA(buf)                                                               \
  {                                                                            \
    _Pragma("unroll")                                                          \
    for (int ks = 0; ks < NKS; ks++) {                                         \
      _Pragma("unroll")                                                        \
      for (int rt = 0; rt < 4; rt++) {                                         \
        int row = rt * 16 + l16;                                               \
        bf16x8 a = *(const bf16x8*)&tile[buf][row * CIN +                      \
                      (((ks * 4 + quad) ^ (row & (CH - 1))) * 8)];             \
        acc[rt][0] = __builtin_amdgcn_mfma_f32_16x16x32_bf16(a, bfr[2 * ks],     acc[rt][0], 0, 0, 0); \
        acc[rt][1] = __builtin_amdgcn_mfma_f32_16x16x32_bf16(a, bfr[2 * ks + 1], acc[rt][1], 0, 0, 0); \
      }                                                                        \
    }                                                                          \
  }

  // ---- prologue ----
  LOADB(0, bfr);
  GATHER(0, grA);

  if constexpr (FUSE) {
    // NiN shortcut: acc += fbraw @ wnt, A-frags straight from global (the 16B
    // A-fragment IS a contiguous row chunk); also covers g(0)'s latency.
#pragma unroll
    for (int ks = 0; ks < CA / 32; ks++) {
      bf16x8 b0 = *(const bf16x8*)&wnt[(colbase + l16) * CA + ks * 32 + quad * 8];
      bf16x8 b1 = *(const bf16x8*)&wnt[(colbase + 16 + l16) * CA + ks * 32 + quad * 8];
#pragma unroll
      for (int rt = 0; rt < 4; rt++) {
        int r = rt * 16 + l16;
        bf16x8 a = bf16x8{0, 0, 0, 0, 0, 0, 0, 0};
        if (r < nrows)
          a = *(const bf16x8*)&fbraw[(size_t)(rowbase + r) * CA + ks * 32 + quad * 8];
        acc[rt][0] = __builtin_amdgcn_mfma_f32_16x16x32_bf16(a, b0, acc[rt][0], 0, 0, 0);
        acc[rt][1] = __builtin_amdgcn_mfma_f32_16x16x32_bf16(a, b1, acc[rt][1], 0, 0, 0);
      }
    }
  }

  STAGE(0, grA);           // waits g(0) only (covered by NiN when FUSE)
  GATHER(1, grA);          // issued after the stage -> stays in flight
  GATHER(2, grB);          // across the barrier
  barrier_lds();

  // ---- steady state: k = 0..21, manual unroll-by-2, static buffer names ----
  {
    int k = 0;
#pragma unroll 1
    for (int kk = 0; kk < 11; kk++, k += 2) {
      // even k: compute tile0, stage g(k+1) from grA, refill grA with g(k+3)
      MMA(0);
      LOADB(k + 1, bfr);
      STAGE(1, grA);
      GATHER(k + 3, grA);
      barrier_lds();
      // odd k+1: compute tile1, stage g(k+2) from grB, refill grB with g(k+4)
      MMA(1);
      LOADB(k + 2, bfr);
      STAGE(0, grB);
      GATHER(k + 4, grB);
      barrier_lds();
    }
  }

  // ---- tail: k = 22..26, statically unrolled (compile-time guards) ----
#pragma unroll
  for (int k2 = 22; k2 < KOFF; k2++) {
    if ((k2 & 1) == 0) {
      MMA(0);
      if (k2 + 1 < KOFF) {
        LOADB(k2 + 1, bfr);
        STAGE(1, grA);
        if (k2 + 3 < KOFF) GATHER(k2 + 3, grA);
        barrier_lds();
      }
    } else {
      MMA(1);
      if (k2 + 1 < KOFF) {
        LOADB(k2 + 1, bfr);
        STAGE(0, grB);
        if (k2 + 3 < KOFF) GATHER(k2 + 3, grB);
        barrier_lds();
      }
    }
  }
#undef LOADB
#undef GATHER
#undef STAGE
#undef MMA

  // epilogue: C/D layout col=lane&15, row=(lane>>4)*4+reg
#pragma unroll
  for (int rt = 0; rt < 4; rt++) {
#pragma unroll
    for (int ct = 0; ct < 2; ct++) {
#pragma unroll
      for (int i = 0; i < 4; i++) {
        int r = rt * 16 + quad * 4 + i;
        if (r < nrows) {
          int c = colbase + ct * 16 + l16;
          out[(size_t)(rowbase + r) * CB + c] = acc[rt][ct][i];
        }
      }
    }
  }

  if constexpr (STATS) {
    // fused next-BN stats: tail rows contribute exact zeros (masked gathers)
#pragma unroll
    for (int ct = 0; ct < 2; ct++) {
      float s = 0.f, q = 0.f;
#pragma unroll
      for (int rt = 0; rt < 4; rt++)
#pragma unroll
        for (int i = 0; i < 4; i++) { float v = acc[rt][ct][i]; s += v; q += v * v; }
      s += __shfl_xor(s, 16); s += __shfl_xor(s, 32);   // reduce over quad lanes
      q += __shfl_xor(q, 16); q += __shfl_xor(q, 32);
      if (quad == 0) {
        int cch = colbase + ct * 16 + l16;
        atomicAdd(&sums[cch], s);
        atomicAdd(&sums[CB + cch], q);
      }
    }
  }
}

extern "C" void kernel_launch(void* const* d_in, const int* in_sizes, int n_in,
                              void* d_out, int out_size, void* d_ws, size_t ws_size,
                              hipStream_t stream) {
  const float* feat   = (const float*)d_in[0];
  const float* gamma1 = (const float*)d_in[1];
  const float* beta1  = (const float*)d_in[2];
  const float* W1     = (const float*)d_in[3];
  const float* gamma2 = (const float*)d_in[4];
  const float* beta2  = (const float*)d_in[5];
  const float* W2     = (const float*)d_in[6];
  const float* Wnin   = (const float*)d_in[7];
  const int*   nbr    = (const int*)d_in[8];
  const void*  mask   = d_in[9];
  float* out = (float*)d_out;

  const int n = in_sizes[0] / CA;  // 100000

  char* ws = (char*)d_ws;
  size_t off = 0;
  auto alloc = [&](size_t bytes) { size_t p = off; off += (bytes + 255) & ~(size_t)255; return p; };
  int*            flag  = (int*)           (ws + alloc(256));
  float*          sums1 = (float*)         (ws + alloc(2 * CA * 4));
  float*          sums2 = (float*)         (ws + alloc(2 * CB * 4));
  float*          sc1   = (float*)         (ws + alloc(2 * CA * 4));
  float*          sc2   = (float*)         (ws + alloc(2 * CB * 4));
  uint32_t*       mbits = (uint32_t*)      (ws + alloc((size_t)n * 4));
  unsigned short* fb    = (unsigned short*)(ws + alloc((size_t)n * CA * 2));
  unsigned short* hb1   = (unsigned short*)(ws + alloc((size_t)n * CA * 2));
  float*          out1  = (float*)         (ws + alloc((size_t)n * CB * 4));
  unsigned short* hb2   = (unsigned short*)(ws + alloc((size_t)n * CB * 2));
  unsigned short* w1t   = (unsigned short*)(ws + alloc((size_t)KOFF * CB * CA * 2));
  unsigned short* w2t   = (unsigned short*)(ws + alloc((size_t)KOFF * CB * CB * 2));
  unsigned short* wnt   = (unsigned short*)(ws + alloc((size_t)CB * CA * 2));

  // zero flag + stats accumulators (ws is poisoned 0xAA before every launch)
  hipMemsetAsync(d_ws, 0, 1792, stream);

  detect_mask_k<<<1, 256, 0, stream>>>((const unsigned char*)mask, flag);
  pack_mask_k<<<(n + 255) / 256, 256, 0, stream>>>(mask, flag, mbits, n);

  {
    int tot = KOFF * CA * CB + KOFF * CB * CB + CA * CB;
    transpose_all_k<<<(tot + 255) / 256, 256, 0, stream>>>(W1, W2, Wnin, w1t, w2t, wnt);
  }

  // stage 1: BN stats -> scale/shift -> h1 (bn+relu bf16) + raw feat bf16
  col_stats_k<CA><<<256, 256, 0, stream>>>(feat, n, sums1);
  bn_finalize_k<CA><<<1, CA, 0, stream>>>(sums1, gamma1, beta1, sc1, n);
  bn_apply_k<CA, true><<<(n * CA / 4 + 255) / 256, 256, 0, stream>>>(feat, sc1, hb1, fb, n * CA);

  // conv1: out1 = subconv(h1, W1)  [N,128] fp32, BN2 stats fused in epilogue
  conv_k<CA, false, true><<<(n + 63) / 64, 256, 0, stream>>>(hb1, w1t, nbr, mbits, nullptr, nullptr, out1, sums2, n);

  // stage 2 (col_stats pass eliminated -- stats came from conv1)
  bn_finalize_k<CB><<<1, CB, 0, stream>>>(sums2, gamma2, beta2, sc2, n);
  bn_apply_k<CB, false><<<(n * CB / 4 + 255) / 256, 256, 0, stream>>>(out1, sc2, hb2, nullptr, n * CB);

  // conv2 + fused NiN shortcut
  conv_k<CB, true, false><<<(n + 63) / 64, 256, 0, stream>>>(hb2, w2t, nbr, mbits, fb, wnt, out, nullptr, n);
}

// Round 3
// 493.055 us; speedup vs baseline: 1.0879x; 1.0329x over previous
//
#include <hip/hip_runtime.h>
#include <stdint.h>

#define CA 64     // in channels
#define CB 128    // out channels
#define KOFF 27   // 3^3 offsets
#define BN_EPS 1e-4f

typedef short bf16x8 __attribute__((ext_vector_type(8)));
typedef float f32x4 __attribute__((ext_vector_type(4)));
typedef unsigned int u32x4 __attribute__((ext_vector_type(4)));
typedef unsigned short u16x4 __attribute__((ext_vector_type(4)));

__device__ __forceinline__ unsigned short f2bf(float f) {
  union { float f; uint32_t u; } c; c.f = f;
  uint32_t u = c.u;
  return (unsigned short)((u + 0x7FFFu + ((u >> 16) & 1u)) >> 16);  // RNE
}

// Barrier WITHOUT vmcnt drain: LDS visibility only. Safe because all cross-wave
// data flows through LDS (ds_write -> lgkmcnt(0) -> s_barrier); in-flight global
// loads target VGPRs only and must stay in flight (that's the pipeline).
__device__ __forceinline__ void barrier_lds() {
  asm volatile("s_waitcnt lgkmcnt(0)\n\ts_barrier" ::: "memory");
}

// ---- mask dtype detection: if int32 layout, bytes at i%4!=0 are all zero ----
__global__ void detect_mask_k(const unsigned char* __restrict__ m, int* flag) {
  unsigned v = 0;
  for (int i = threadIdx.x; i < 4096; i += 256)
    if (i & 3) v |= m[i];
  if (v) atomicOr(flag, 1);   // 1 => byte/bool layout, 0 => int32 layout
}

__global__ void pack_mask_k(const void* __restrict__ mp, const int* __restrict__ flag,
                            uint32_t* __restrict__ bits, int n) {
  int i = blockIdx.x * blockDim.x + threadIdx.x;
  if (i >= n) return;
  uint32_t b = 0;
  if (*flag) {
    const unsigned char* m = (const unsigned char*)mp + (size_t)i * KOFF;
    for (int k = 0; k < KOFF; k++) b |= (m[k] ? 1u : 0u) << k;
  } else {
    const int* m = (const int*)mp + (size_t)i * KOFF;
    for (int k = 0; k < KOFF; k++) b |= (m[k] ? 1u : 0u) << k;
  }
  bits[i] = b;
}

// ---- all weight transposes + bf16 convert in one launch ----
// wt[k][co][ci] = bf16(w[k][ci][co])
__global__ void transpose_all_k(const float* __restrict__ W1, const float* __restrict__ W2,
                                const float* __restrict__ Wnin,
                                unsigned short* __restrict__ w1t, unsigned short* __restrict__ w2t,
                                unsigned short* __restrict__ wnt) {
  const int t1 = KOFF * CA * CB, t2 = KOFF * CB * CB, t3 = CA * CB;
  int idx = blockIdx.x * blockDim.x + threadIdx.x;
  if (idx < t1) {
    int ci = idx % CA; int r = idx / CA; int co = r % CB; int k = r / CB;
    w1t[idx] = f2bf(W1[((size_t)k * CA + ci) * CB + co]);
  } else if (idx < t1 + t2) {
    int j = idx - t1;
    int ci = j % CB; int r = j / CB; int co = r % CB; int k = r / CB;
    w2t[j] = f2bf(W2[((size_t)k * CB + ci) * CB + co]);
  } else if (idx < t1 + t2 + t3) {
    int j = idx - t1 - t2;
    int ci = j % CA; int co = j / CA;
    wnt[j] = f2bf(Wnin[(size_t)ci * CB + co]);
  }
}

// ---- per-channel sum & sumsq (training-mode BN stats) ----
template<int C>
__global__ void col_stats_k(const float* __restrict__ x, int n, float* __restrict__ sums) {
  __shared__ float ssum[C], ssq[C];
  int t = threadIdx.x;
  for (int i = t; i < C; i += 256) { ssum[i] = 0.f; ssq[i] = 0.f; }
  __syncthreads();
  const int c = t % C;
  const int rpb = 256 / C;
  float s = 0.f, q = 0.f;
  for (int r = blockIdx.x * rpb + t / C; r < n; r += gridDim.x * rpb) {
    float v = x[(size_t)r * C + c];
    s += v; q += v * v;
  }
  atomicAdd(&ssum[c], s);
  atomicAdd(&ssq[c], q);
  __syncthreads();
  for (int i = t; i < C; i += 256) {
    atomicAdd(&sums[i], ssum[i]);
    atomicAdd(&sums[C + i], ssq[i]);
  }
}

template<int C>
__global__ void bn_finalize_k(const float* __restrict__ sums, const float* __restrict__ gamma,
                              const float* __restrict__ beta, float* __restrict__ sc, int n) {
  int c = threadIdx.x;
  if (c >= C) return;
  float inv_n = 1.f / (float)n;
  float mean = sums[c] * inv_n;
  float var = sums[C + c] * inv_n - mean * mean;
  float rstd = rsqrtf(var + BN_EPS);
  float scale = gamma[c] * rstd;
  sc[c] = scale;
  sc[C + c] = beta[c] - mean * scale;
}

template<int C, bool RAW>
__global__ void bn_apply_k(const float* __restrict__ x, const float* __restrict__ sc,
                           unsigned short* __restrict__ h, unsigned short* __restrict__ raw,
                           int total) {
  int idx = (blockIdx.x * blockDim.x + threadIdx.x) * 4;
  if (idx >= total) return;
  f32x4 v = *(const f32x4*)&x[idx];
  int c0 = idx % C;
  u16x4 ho, ro;
#pragma unroll
  for (int j = 0; j < 4; j++) {
    float s = sc[c0 + j], b = sc[C + c0 + j];
    float hv = fmaxf(v[j] * s + b, 0.f);
    ho[j] = f2bf(hv);
    if (RAW) ro[j] = f2bf(v[j]);
  }
  *(u16x4*)&h[idx] = ho;
  if (RAW) *(u16x4*)&raw[idx] = ro;
}

// ---- pipelined gather-GEMM subconv ----
// out[n,:] = sum_k mask[n,k] * hin[nbr[n,k],:] @ W[k]   (+ FUSE: fbraw @ wnt)
// Block: 64 rows x 128 cols, 256 threads (4 waves of 64x32).
// FULL 27-way unroll (one straight-line region): the scheduler interleaves
// loads/MFMAs ACROSS barrier_lds boundaries -- R2 proved a rolled loop
// (#pragma unroll 1) loses ~7% because nothing hoists past the barrier asm.
// 2-deep gather pipeline via named grA/grB selected by compile-time parity
// (all register indices static -> no scratch). B-frags single-deep, reloaded
// per k (weights L2-hot). LDS unpadded + XOR chunk-swizzle (same involution
// write & read) -> 0 bank conflicts, 39.9KB/block -> 4 blocks/CU for CIN=128.
// NO __launch_bounds__ min-occupancy: R1 showed it forces a 16-dword spill.
template<int CIN, bool FUSE, bool STATS>
__launch_bounds__(256)
__global__ void conv_k(const unsigned short* __restrict__ hin,
                       const unsigned short* __restrict__ wt,
                       const int* __restrict__ nbr,
                       const uint32_t* __restrict__ mbits,
                       const unsigned short* __restrict__ fbraw,
                       const unsigned short* __restrict__ wnt,
                       float* __restrict__ out, float* __restrict__ sums, int n) {
  constexpr int TR = 64;
  constexpr int NKS = CIN / 32;     // MFMA K-steps per offset (2 or 4)
  constexpr int CH = CIN / 8;       // 16B chunks per row (8 or 16)
  constexpr int RPP = 256 / CH;     // rows per staging pass
  constexpr int NP = TR / RPP;      // staging passes per thread (2 or 4)

  __shared__ alignas(16) unsigned short tile[2][TR * CIN];
  __shared__ int lnbr[TR * KOFF];   // pre-multiplied byte offsets
  __shared__ uint32_t lmb[TR];

  const int t = threadIdx.x;
  const int rowbase = blockIdx.x * TR;
  const int nrows = min(TR, n - rowbase);

  for (int i = t; i < nrows * KOFF; i += 256)
    lnbr[i] = nbr[(size_t)rowbase * KOFF + i] * (CIN * 2);
  if (t < TR) lmb[t] = (t < nrows) ? mbits[rowbase + t] : 0u;
  barrier_lds();

  const int lane = t & 63;
  const int wave = t >> 6;
  const int l16 = lane & 15;
  const int quad = lane >> 4;
  const int colbase = wave * 32;
  const int c16 = t % CH;           // 16B chunk index within row
  const int grow = t / CH;          // row within a staging pass
  const int boff0 = (colbase + l16) * CIN + quad * 8;
  const int boff1 = boff0 + 16 * CIN;
  // RPP is a multiple of CH, so (p*RPP+grow)&(CH-1) == grow&(CH-1):
  // swizzle term is p-invariant -> single base + compile-time p offsets.
  const int tbase = grow * CIN + ((c16 ^ (grow & (CH - 1))) * 8);
  const int growK = grow * KOFF;

  uint32_t pmb[NP];
#pragma unroll
  for (int p = 0; p < NP; p++) pmb[p] = lmb[p * RPP + grow];

  f32x4 acc[4][2];
#pragma unroll
  for (int i = 0; i < 4; i++) { acc[i][0] = f32x4{0,0,0,0}; acc[i][1] = f32x4{0,0,0,0}; }

  bf16x8 bfr[2 * NKS];     // single-deep B fragments
  u32x4 grA[NP], grB[NP];  // named 2-deep gather pipeline (static indexing)

#define LOADB(kk, dst)                                                         \
  {                                                                            \
    const unsigned short* wk = wt + (size_t)(kk) * (CB * CIN);                 \
    _Pragma("unroll")                                                          \
    for (int ks = 0; ks < NKS; ks++) {                                         \
      dst[2 * ks]     = *(const bf16x8*)&wk[boff0 + ks * 32];                  \
      dst[2 * ks + 1] = *(const bf16x8*)&wk[boff1 + ks * 32];                  \
    }                                                                          \
  }

#define GATHER(kk, dst)                                                        \
  {                                                                            \
    _Pragma("unroll")                                                          \
    for (int p = 0; p < NP; p++) {                                             \
      u32x4 v = {0, 0, 0, 0};                                                  \
      if ((pmb[p] >> (kk)) & 1u)                                               \
        v = *(const u32x4*)((const char*)hin +                                 \
             (size_t)(unsigned)lnbr[p * RPP * KOFF + growK + (kk)] + c16 * 16);\
      dst[p] = v;                                                              \
    }                                                                          \
  }

#define STAGE(buf, src)                                                        \
  {                                                                            \
    _Pragma("unroll")                                                          \
    for (int p = 0; p < NP; p++)                                               \
      *(u32x4*)&tile[buf][tbase + p * RPP * CIN] = src[p];                     \
  }

#define MMA(buf)                                                               \
  {                                                                            \
    _Pragma("unroll")                                                          \
    for (int ks = 0; ks < NKS; ks++) {                                         \
      _Pragma("unroll")                                                        \
      for (int rt = 0; rt < 4; rt++) {                                         \
        int row = rt * 16 + l16;                                               \
        bf16x8 a = *(const bf16x8*)&tile[buf][row * CIN +                      \
                      (((ks * 4 + quad) ^ (row & (CH - 1))) * 8)];             \
        acc[rt][0] = __builtin_amdgcn_mfma_f32_16x16x32_bf16(a, bfr[2 * ks],     acc[rt][0], 0, 0, 0); \
        acc[rt][1] = __builtin_amdgcn_mfma_f32_16x16x32_bf16(a, bfr[2 * ks + 1], acc[rt][1], 0, 0, 0); \
      }                                                                        \
    }                                                                          \
  }

  // ---- prologue ----
  LOADB(0, bfr);
  GATHER(0, grA);

  if constexpr (FUSE) {
    // NiN shortcut: acc += fbraw @ wnt, A-frags straight from global (the 16B
    // A-fragment IS a contiguous row chunk); also covers g(0)'s latency.
#pragma unroll
    for (int ks = 0; ks < CA / 32; ks++) {
      bf16x8 b0 = *(const bf16x8*)&wnt[(colbase + l16) * CA + ks * 32 + quad * 8];
      bf16x8 b1 = *(const bf16x8*)&wnt[(colbase + 16 + l16) * CA + ks * 32 + quad * 8];
#pragma unroll
      for (int rt = 0; rt < 4; rt++) {
        int r = rt * 16 + l16;
        bf16x8 a = bf16x8{0, 0, 0, 0, 0, 0, 0, 0};
        if (r < nrows)
          a = *(const bf16x8*)&fbraw[(size_t)(rowbase + r) * CA + ks * 32 + quad * 8];
        acc[rt][0] = __builtin_amdgcn_mfma_f32_16x16x32_bf16(a, b0, acc[rt][0], 0, 0, 0);
        acc[rt][1] = __builtin_amdgcn_mfma_f32_16x16x32_bf16(a, b1, acc[rt][1], 0, 0, 0);
      }
    }
  }

  STAGE(0, grA);           // waits g(0) only (covered by NiN when FUSE)
  GATHER(1, grA);          // issued after the stage -> stays in flight
  GATHER(2, grB);          // across the barrier
  barrier_lds();

  // ---- main loop: FULL unroll, parity-static buffer names ----
#pragma unroll
  for (int k = 0; k < KOFF; k++) {
    if ((k & 1) == 0) {
      MMA(0);
      if (k + 1 < KOFF) {
        LOADB(k + 1, bfr);
        STAGE(1, grA);                       // g(k+1), gathered 2 iters ago
        if (k + 3 < KOFF) GATHER(k + 3, grA);
        barrier_lds();
      }
    } else {
      MMA(1);
      if (k + 1 < KOFF) {
        LOADB(k + 1, bfr);
        STAGE(0, grB);
        if (k + 3 < KOFF) GATHER(k + 3, grB);
        barrier_lds();
      }
    }
  }
#undef LOADB
#undef GATHER
#undef STAGE
#undef MMA

  // epilogue: C/D layout col=lane&15, row=(lane>>4)*4+reg
#pragma unroll
  for (int rt = 0; rt < 4; rt++) {
#pragma unroll
    for (int ct = 0; ct < 2; ct++) {
#pragma unroll
      for (int i = 0; i < 4; i++) {
        int r = rt * 16 + quad * 4 + i;
        if (r < nrows) {
          int c = colbase + ct * 16 + l16;
          out[(size_t)(rowbase + r) * CB + c] = acc[rt][ct][i];
        }
      }
    }
  }

  if constexpr (STATS) {
    // fused next-BN stats: tail rows contribute exact zeros (masked gathers)
#pragma unroll
    for (int ct = 0; ct < 2; ct++) {
      float s = 0.f, q = 0.f;
#pragma unroll
      for (int rt = 0; rt < 4; rt++)
#pragma unroll
        for (int i = 0; i < 4; i++) { float v = acc[rt][ct][i]; s += v; q += v * v; }
      s += __shfl_xor(s, 16); s += __shfl_xor(s, 32);   // reduce over quad lanes
      q += __shfl_xor(q, 16); q += __shfl_xor(q, 32);
      if (quad == 0) {
        int cch = colbase + ct * 16 + l16;
        atomicAdd(&sums[cch], s);
        atomicAdd(&sums[CB + cch], q);
      }
    }
  }
}

extern "C" void kernel_launch(void* const* d_in, const int* in_sizes, int n_in,
                              void* d_out, int out_size, void* d_ws, size_t ws_size,
                              hipStream_t stream) {
  const float* feat   = (const float*)d_in[0];
  const float* gamma1 = (const float*)d_in[1];
  const float* beta1  = (const float*)d_in[2];
  const float* W1     = (const float*)d_in[3];
  const float* gamma2 = (const float*)d_in[4];
  const float* beta2  = (const float*)d_in[5];
  const float* W2     = (const float*)d_in[6];
  const float* Wnin   = (const float*)d_in[7];
  const int*   nbr    = (const int*)d_in[8];
  const void*  mask   = d_in[9];
  float* out = (float*)d_out;

  const int n = in_sizes[0] / CA;  // 100000

  char* ws = (char*)d_ws;
  size_t off = 0;
  auto alloc = [&](size_t bytes) { size_t p = off; off += (bytes + 255) & ~(size_t)255; return p; };
  int*            flag  = (int*)           (ws + alloc(256));
  float*          sums1 = (float*)         (ws + alloc(2 * CA * 4));
  float*          sums2 = (float*)         (ws + alloc(2 * CB * 4));
  float*          sc1   = (float*)         (ws + alloc(2 * CA * 4));
  float*          sc2   = (float*)         (ws + alloc(2 * CB * 4));
  uint32_t*       mbits = (uint32_t*)      (ws + alloc((size_t)n * 4));
  unsigned short* fb    = (unsigned short*)(ws + alloc((size_t)n * CA * 2));
  unsigned short* hb1   = (unsigned short*)(ws + alloc((size_t)n * CA * 2));
  float*          out1  = (float*)         (ws + alloc((size_t)n * CB * 4));
  unsigned short* hb2   = (unsigned short*)(ws + alloc((size_t)n * CB * 2));
  unsigned short* w1t   = (unsigned short*)(ws + alloc((size_t)KOFF * CB * CA * 2));
  unsigned short* w2t   = (unsigned short*)(ws + alloc((size_t)KOFF * CB * CB * 2));
  unsigned short* wnt   = (unsigned short*)(ws + alloc((size_t)CB * CA * 2));

  // zero flag + stats accumulators (ws is poisoned 0xAA before every launch)
  hipMemsetAsync(d_ws, 0, 1792, stream);

  detect_mask_k<<<1, 256, 0, stream>>>((const unsigned char*)mask, flag);
  pack_mask_k<<<(n + 255) / 256, 256, 0, stream>>>(mask, flag, mbits, n);

  {
    int tot = KOFF * CA * CB + KOFF * CB * CB + CA * CB;
    transpose_all_k<<<(tot + 255) / 256, 256, 0, stream>>>(W1, W2, Wnin, w1t, w2t, wnt);
  }

  // stage 1: BN stats -> scale/shift -> h1 (bn+relu bf16) + raw feat bf16
  col_stats_k<CA><<<256, 256, 0, stream>>>(feat, n, sums1);
  bn_finalize_k<CA><<<1, CA, 0, stream>>>(sums1, gamma1, beta1, sc1, n);
  bn_apply_k<CA, true><<<(n * CA / 4 + 255) / 256, 256, 0, stream>>>(feat, sc1, hb1, fb, n * CA);

  // conv1: out1 = subconv(h1, W1)  [N,128] fp32, BN2 stats fused in epilogue
  conv_k<CA, false, true><<<(n + 63) / 64, 256, 0, stream>>>(hb1, w1t, nbr, mbits, nullptr, nullptr, out1, sums2, n);

  // stage 2 (col_stats pass eliminated -- stats came from conv1)
  bn_finalize_k<CB><<<1, CB, 0, stream>>>(sums2, gamma2, beta2, sc2, n);
  bn_apply_k<CB, false><<<(n * CB / 4 + 255) / 256, 256, 0, stream>>>(out1, sc2, hb2, nullptr, n * CB);

  // conv2 + fused NiN shortcut
  conv_k<CB, true, false><<<(n + 63) / 64, 256, 0, stream>>>(hb2, w2t, nbr, mbits, fb, wnt, out, nullptr, n);
}